// Round 7
// baseline (30.221 us; speedup 1.0000x reference)
//
#include <hip/hip_runtime.h>
#include <hip/hip_bf16.h>
#include <math.h>

// Problem constants (from reference)
#define NB     128
#define NT_ALL 197
#define NT     196
#define ND     768
#define NORG   5
#define NE     8
#define NCLS   100
#define NCOL   105            // 100 cls + 5 aux columns
#define NTOK   (NB * NT)      // 25088
#define KB     24             // 768 / 32 k-blocks
#define PF     6              // x-prefetch depth (k-blocks in flight)

#define RBLKS  392            // router blocks first: 392 * 4 waves * 16 tokens
#define CBLKS  256            // cls blocks after

#define NFRAG  (KB * 64)      // 1536 A-fragments (16B each) in ws
#define WS_A_BYTES  (NFRAG * 16)          // 24576
#define WS_PL_OFF   WS_A_BYTES            // float pl[NB][NE] after table

typedef short  bf16x8 __attribute__((ext_vector_type(8)));
typedef float  f32x4  __attribute__((ext_vector_type(4)));

// Output layout (flat, concatenated in return order):
//   logits  : NB*NCLS = 12800   @ 0
//   aux_org : NB*NORG = 640     @ 12800
//   probs   : NTOK*NE = 200704  @ 13440
//   entropy : NTOK    = 25088   @ 214144

// ---------------------------------------------------------------------------
// Prepass: build (a) bf16 A-fragment table for W^T in MFMA fragment order
// [kb][g][e][8], e in 0..15 with e>=8 zero  (frag idx = kb*64 + g*16 + e);
// (b) prior+bias logits pl[b][e]. Both into d_ws.
// ---------------------------------------------------------------------------
__global__ __launch_bounds__(256) void prepass_kernel(
    const float* __restrict__ rw,        // (ND+NORG, NE)
    const float* __restrict__ rbias,     // (NE,)
    const float* __restrict__ priors,    // (NB, NORG)
    __hip_bfloat16* __restrict__ ws_a,   // NFRAG * 8 bf16
    float* __restrict__ ws_pl)           // NB * NE
{
    const int gi = blockIdx.x * 256 + threadIdx.x;
    if (gi < NFRAG) {
        const int e  = gi & 15;
        const int kg = gi >> 4;          // k-octet index 0..95 (k = kg*8+j)
        union { bf16x8 v; __hip_bfloat16 h[8]; } u;
        if (e < 8) {
#pragma unroll
            for (int j = 0; j < 8; ++j)
                u.h[j] = __float2bfloat16(rw[(kg * 8 + j) * NE + e]);
        } else {
#pragma unroll
            for (int j = 0; j < 8; ++j)
                u.h[j] = __float2bfloat16(0.f);
        }
        reinterpret_cast<bf16x8*>(ws_a)[gi] = u.v;
    } else if (gi < NFRAG + NB * NE) {
        const int i = gi - NFRAG;
        const int b = i >> 3, e = i & 7;
        float a = rbias[e];
#pragma unroll
        for (int o = 0; o < NORG; ++o)
            a = fmaf(priors[b * NORG + o], rw[(ND + o) * NE + e], a);
        ws_pl[i] = a;
    }
}

// ---------------------------------------------------------------------------
// Fused main kernel. Blocks [0,392): router (4 indep waves, 16 tokens each,
// NO LDS / NO barrier — A-fragments read coalesced from the L1-hot ws table).
// Blocks [392,648): CLS head (unchanged).
// ---------------------------------------------------------------------------
__global__ __launch_bounds__(256, 4) void fused_kernel(
    const float* __restrict__ tokens,    // (NB, NT_ALL, ND)
    const __hip_bfloat16* __restrict__ ws_a,
    const float* __restrict__ ws_pl,     // (NB, NE)
    const float* __restrict__ ln_g, const float* __restrict__ ln_b,
    const float* __restrict__ cls_w,     // (ND, NCLS)
    const float* __restrict__ cls_b,     // (NCLS,)
    const float* __restrict__ aux_w,     // (ND, NORG)
    const float* __restrict__ aux_b,     // (NORG,)
    float* __restrict__ out_logits,      // (NB, NCLS)
    float* __restrict__ out_aux,         // (NB, NORG)
    float* __restrict__ probs_out,       // (NTOK, NE)
    float* __restrict__ ent_out)         // (NTOK,)
{
    const int t = threadIdx.x;

    if (blockIdx.x < RBLKS) {
        // ------------------------------ router ------------------------------
        const int wid  = t >> 6;
        const int lane = t & 63;
        const int tt   = lane & 15;      // token col / expert row
        const int g    = lane >> 4;      // k-octet selector
        const int token = (blockIdx.x * 4 + wid) * 16 + tt;
        const int b  = token / NT;
        const float* xp = tokens + ((size_t)b * NT_ALL + 1 + (token - b * NT)) * ND
                          + g * 8;
        const bf16x8* afp = reinterpret_cast<const bf16x8*>(ws_a) + lane;

        // Prologue x-prefetch ring.
        float4 xb[PF][2];
#pragma unroll
        for (int i = 0; i < PF; ++i) {
            xb[i][0] = *reinterpret_cast<const float4*>(xp + i * 32);
            xb[i][1] = *reinterpret_cast<const float4*>(xp + i * 32 + 4);
        }
        bf16x8 af_cur = afp[0];

        f32x4 acc0 = {0.f, 0.f, 0.f, 0.f};
        f32x4 acc1 = {0.f, 0.f, 0.f, 0.f};

#pragma unroll
        for (int kb = 0; kb < KB; ++kb) {
            const bf16x8 af_next = (kb + 1 < KB) ? afp[(kb + 1) * 64] : af_cur;
            const float4 x0 = xb[kb % PF][0];
            const float4 x1 = xb[kb % PF][1];
            union { bf16x8 v; __hip_bfloat16 h[8]; } u;
            u.h[0] = __float2bfloat16(x0.x);
            u.h[1] = __float2bfloat16(x0.y);
            u.h[2] = __float2bfloat16(x0.z);
            u.h[3] = __float2bfloat16(x0.w);
            u.h[4] = __float2bfloat16(x1.x);
            u.h[5] = __float2bfloat16(x1.y);
            u.h[6] = __float2bfloat16(x1.z);
            u.h[7] = __float2bfloat16(x1.w);
            if (kb & 1)
                acc1 = __builtin_amdgcn_mfma_f32_16x16x32_bf16(af_cur, u.v, acc1, 0, 0, 0);
            else
                acc0 = __builtin_amdgcn_mfma_f32_16x16x32_bf16(af_cur, u.v, acc0, 0, 0, 0);
            if (kb + PF < KB) {
                xb[kb % PF][0] = *reinterpret_cast<const float4*>(xp + (kb + PF) * 32);
                xb[kb % PF][1] = *reinterpret_cast<const float4*>(xp + (kb + PF) * 32 + 4);
            }
            af_cur = af_next;
        }
        const f32x4 acc = acc0 + acc1;

        // Gather the other 4 experts from lane^16.
        const float p0 = __shfl_xor(acc[0], 16, 64);
        const float p1 = __shfl_xor(acc[1], 16, 64);
        const float p2 = __shfl_xor(acc[2], 16, 64);
        const float p3 = __shfl_xor(acc[3], 16, 64);

        if (lane < 16) {
            float lg[NE] = {acc[0], acc[1], acc[2], acc[3], p0, p1, p2, p3};
            const float4 pl0 = *reinterpret_cast<const float4*>(ws_pl + b * NE);
            const float4 pl1 = *reinterpret_cast<const float4*>(ws_pl + b * NE + 4);
            lg[0] += pl0.x; lg[1] += pl0.y; lg[2] += pl0.z; lg[3] += pl0.w;
            lg[4] += pl1.x; lg[5] += pl1.y; lg[6] += pl1.z; lg[7] += pl1.w;

            // softmax + entropy: ent = ln(S) - (sum p*l)/S, l = logit - max
            float m = lg[0];
#pragma unroll
            for (int e = 1; e < NE; ++e) m = fmaxf(m, lg[e]);
            float S = 0.f, dd = 0.f;
#pragma unroll
            for (int e = 0; e < NE; ++e) {
                const float l = lg[e] - m;
                const float p = __expf(l);
                lg[e] = p;
                S += p;
                dd = fmaf(p, l, dd);
            }
            const float inv = 1.f / S;
            const float ent = __logf(S) - dd * inv;

            float4 q0 = {lg[0] * inv, lg[1] * inv, lg[2] * inv, lg[3] * inv};
            float4 q1 = {lg[4] * inv, lg[5] * inv, lg[6] * inv, lg[7] * inv};
            *reinterpret_cast<float4*>(probs_out + (size_t)token * NE)     = q0;
            *reinterpret_cast<float4*>(probs_out + (size_t)token * NE + 4) = q1;
            ent_out[token] = ent;
        }
    } else {
        // ------------------------------ CLS head ----------------------------
        const int cb   = blockIdx.x - RBLKS;     // 0..255
        const int b    = cb >> 1;
        const int half = cb & 1;
        const int lane = t & 63;
        const int wv   = t >> 6;                 // 0..3

        __shared__ __align__(16) float s_x[ND];
        __shared__ float s_red[4];
        __shared__ float s_part[4][65];

        const float* xp = tokens + (size_t)b * NT_ALL * ND;  // cls token

        float sum = 0.f;
        for (int i = t; i < ND; i += 256) { float v = xp[i]; s_x[i] = v; sum += v; }
#pragma unroll
        for (int off = 32; off; off >>= 1) sum += __shfl_xor(sum, off, 64);
        if (lane == 0) s_red[wv] = sum;
        __syncthreads();
        const float mu = (s_red[0] + s_red[1] + s_red[2] + s_red[3]) * (1.f / ND);
        __syncthreads();

        float sq = 0.f;
        for (int i = t; i < ND; i += 256) { float d = s_x[i] - mu; sq += d * d; }
#pragma unroll
        for (int off = 32; off; off >>= 1) sq += __shfl_xor(sq, off, 64);
        if (lane == 0) s_red[wv] = sq;
        __syncthreads();
        const float var  = (s_red[0] + s_red[1] + s_red[2] + s_red[3]) * (1.f / ND);
        const float rstd = rsqrtf(var + 1e-5f);
        __syncthreads();

        for (int i = t; i < ND; i += 256)
            s_x[i] = (s_x[i] - mu) * rstd * ln_g[i] + ln_b[i];
        __syncthreads();

        const int c = half * 64 + lane;
        const float* wp; int st;
        if (c < NCLS)      { wp = cls_w + c;          st = NCLS; }
        else if (c < NCOL) { wp = aux_w + (c - NCLS); st = NORG; }
        else               { wp = aux_w;              st = NORG; }

        const int d0 = wv * 192;
        const float* w = wp + (size_t)d0 * st;
        const int st2 = 2 * st, st3 = 3 * st, st4 = 4 * st;
        float a0 = 0.f, a1 = 0.f, a2 = 0.f, a3 = 0.f;
#pragma unroll 8
        for (int j = 0; j < 192; j += 4) {
            const float4 x4 = *reinterpret_cast<const float4*>(&s_x[d0 + j]);
            a0 = fmaf(x4.x, w[0],   a0);
            a1 = fmaf(x4.y, w[st],  a1);
            a2 = fmaf(x4.z, w[st2], a2);
            a3 = fmaf(x4.w, w[st3], a3);
            w += st4;
        }
        s_part[wv][lane] = (a0 + a1) + (a2 + a3);
        __syncthreads();

        if (t < 64) {
            float r = s_part[0][t] + s_part[1][t] + s_part[2][t] + s_part[3][t];
            const int cc = half * 64 + t;
            if (cc < NCLS)
                out_logits[b * NCLS + cc] = r + cls_b[cc];
            else if (cc < NCOL)
                out_aux[b * NORG + (cc - NCLS)] = r + aux_b[cc - NCLS];
        }
    }
}

extern "C" void kernel_launch(void* const* d_in, const int* in_sizes, int n_in,
                              void* d_out, int out_size, void* d_ws, size_t ws_size,
                              hipStream_t stream) {
    const float* tokens = (const float*)d_in[0];
    const float* priors = (const float*)d_in[1];
    const float* rw     = (const float*)d_in[2];
    const float* rbias  = (const float*)d_in[3];
    // d_in[4..7] = w1,b1,w2,b2 : dead code (MoE output unused by reference)
    const float* ln_g   = (const float*)d_in[8];
    const float* ln_b   = (const float*)d_in[9];
    const float* cls_w  = (const float*)d_in[10];
    const float* cls_b  = (const float*)d_in[11];
    const float* aux_w  = (const float*)d_in[12];
    const float* aux_b  = (const float*)d_in[13];

    float* out = (float*)d_out;
    float* out_logits = out;                                   // 12800
    float* out_aux    = out + NB * NCLS;                       // +640
    float* out_probs  = out + NB * NCLS + NB * NORG;           // +200704
    float* out_ent    = out + NB * NCLS + NB * NORG + (size_t)NTOK * NE;

    __hip_bfloat16* ws_a = (__hip_bfloat16*)d_ws;
    float*          ws_pl = (float*)((char*)d_ws + WS_PL_OFF);

    const int pre_items = NFRAG + NB * NE;
    prepass_kernel<<<(pre_items + 255) / 256, 256, 0, stream>>>(
        rw, rbias, priors, ws_a, ws_pl);

    fused_kernel<<<RBLKS + CBLKS, 256, 0, stream>>>(
        tokens, ws_a, ws_pl, ln_g, ln_b, cls_w, cls_b, aux_w, aux_b,
        out_logits, out_aux, out_probs, out_ent);
}

// Round 8
// 29.598 us; speedup vs baseline: 1.0210x; 1.0210x over previous
//
#include <hip/hip_runtime.h>
#include <hip/hip_bf16.h>
#include <math.h>

// Problem constants (from reference)
#define NB     128
#define NT_ALL 197
#define NT     196
#define ND     768
#define NORG   5
#define NE     8
#define NCLS   100
#define NCOL   105            // 100 cls + 5 aux columns
#define NTOK   (NB * NT)      // 25088
#define KB     24             // 768 / 32 k-blocks total
#define KHALF  12             // k-blocks per wave (K split across wave pair)
#define PF     6              // x-prefetch depth (k-blocks in flight)

#define RBLKS  784            // router blocks: 784 * 2 tiles * 16 tokens = 25088
#define CBLKS  256            // cls blocks after

typedef short  bf16x8 __attribute__((ext_vector_type(8)));
typedef float  f32x4  __attribute__((ext_vector_type(4)));

// Output layout (flat, concatenated in return order):
//   logits  : NB*NCLS = 12800   @ 0
//   aux_org : NB*NORG = 640     @ 12800
//   probs   : NTOK*NE = 200704  @ 13440
//   entropy : NTOK    = 25088   @ 214144

// ---------------------------------------------------------------------------
// Router-as-GEMM with K-split wave pairs.
// D[e][t] = sum_k W[k][e] * X[t][k] via mfma_f32_16x16x32_bf16.
// Tile = 16 tokens x 8 experts. Each tile computed by TWO waves (K-halves of
// 384 dims each); partials combined via LDS. 2 tiles per block -> 4 waves.
// A-fragments ([kb][g][e][8], e>=8 zero) staged in LDS once per block.
// ---------------------------------------------------------------------------
__global__ __launch_bounds__(256, 4) void fused_kernel(
    const float* __restrict__ tokens,    // (NB, NT_ALL, ND)
    const float* __restrict__ priors,    // (NB, NORG)
    const float* __restrict__ rw,        // (ND+NORG, NE) row-major
    const float* __restrict__ rbias,     // (NE,)
    const float* __restrict__ ln_g, const float* __restrict__ ln_b,
    const float* __restrict__ cls_w,     // (ND, NCLS)
    const float* __restrict__ cls_b,     // (NCLS,)
    const float* __restrict__ aux_w,     // (ND, NORG)
    const float* __restrict__ aux_b,     // (NORG,)
    float* __restrict__ out_logits,      // (NB, NCLS)
    float* __restrict__ out_aux,         // (NB, NORG)
    float* __restrict__ probs_out,       // (NTOK, NE)
    float* __restrict__ ent_out)         // (NTOK,)
{
    const int t = threadIdx.x;

    if (blockIdx.x < RBLKS) {
        // ------------------------------ router ------------------------------
        __shared__ __align__(16) __hip_bfloat16 s_a[KB * 4 * 16 * 8]; // 24KB
        __shared__ float s_pl[2][NE];
        __shared__ __align__(16) float s_acc[2][64][4];               // 2KB

        const int wid  = t >> 6;
        const int lane = t & 63;
        const int pair = wid >> 1;       // tile within block (0,1)
        const int half = wid & 1;        // K-half (0: kb 0-11, 1: kb 12-23)
        const int tt   = lane & 15;      // token col / expert row
        const int g    = lane >> 4;      // k-octet selector
        const int tok0 = blockIdx.x * 32;
        const int token = tok0 + pair * 16 + tt;
        const int b  = token / NT;
        const float* xp = tokens + ((size_t)b * NT_ALL + 1 + (token - b * NT)) * ND
                          + half * (KHALF * 32) + g * 8;

        // Prologue x-prefetch (issued BEFORE staging: latency hides under it).
        float4 xb[PF][2];
#pragma unroll
        for (int i = 0; i < PF; ++i) {
            xb[i][0] = *reinterpret_cast<const float4*>(xp + i * 32);
            xb[i][1] = *reinterpret_cast<const float4*>(xp + i * 32 + 4);
        }

        // Zero-init ONLY the e>=8 padding rows (disjoint from fill below).
        {
            bf16x8 z = {0, 0, 0, 0, 0, 0, 0, 0};
            bf16x8* p = (bf16x8*)s_a;
            for (int i = t; i < KB * 4 * 8; i += 256)
                p[(i >> 3) * 16 + 8 + (i & 7)] = z;
        }
        // Fill real experts (e<8): coalesced rw reads, scattered b16 writes.
        for (int i = t; i < ND * NE; i += 256) {
            const int k = i >> 3, e = i & 7;
            const int kb = k >> 5, gg = (k >> 3) & 3, j = k & 7;
            s_a[(((kb * 4 + gg) * 16) + e) * 8 + j] = __float2bfloat16(rw[i]);
        }
        // Prior+bias logits for the (at most 2) batch rows this block spans.
        const int b0 = tok0 / NT;
        const int b1 = (tok0 + 31) / NT;
        if (t < 16) {
            const int e = t & 7, which = t >> 3;
            const int bb = which ? b1 : b0;
            float a = rbias[e];
#pragma unroll
            for (int o = 0; o < NORG; ++o)
                a = fmaf(priors[bb * NORG + o], rw[(ND + o) * NE + e], a);
            s_pl[which][e] = a;
        }
        __syncthreads();   // staging complete

        const bf16x8* s_a8 = (const bf16x8*)s_a + (half * KHALF * 4 + g) * 16 + tt;
        f32x4 acc0 = {0.f, 0.f, 0.f, 0.f};
        f32x4 acc1 = {0.f, 0.f, 0.f, 0.f};

#pragma unroll
        for (int kb = 0; kb < KHALF; ++kb) {
            const float4 x0 = xb[kb % PF][0];
            const float4 x1 = xb[kb % PF][1];
            union { bf16x8 v; __hip_bfloat16 h[8]; } u;
            u.h[0] = __float2bfloat16(x0.x);
            u.h[1] = __float2bfloat16(x0.y);
            u.h[2] = __float2bfloat16(x0.z);
            u.h[3] = __float2bfloat16(x0.w);
            u.h[4] = __float2bfloat16(x1.x);
            u.h[5] = __float2bfloat16(x1.y);
            u.h[6] = __float2bfloat16(x1.z);
            u.h[7] = __float2bfloat16(x1.w);
            const bf16x8 af = s_a8[kb * 64];
            if (kb & 1)
                acc1 = __builtin_amdgcn_mfma_f32_16x16x32_bf16(af, u.v, acc1, 0, 0, 0);
            else
                acc0 = __builtin_amdgcn_mfma_f32_16x16x32_bf16(af, u.v, acc0, 0, 0, 0);
            if (kb + PF < KHALF) {
                xb[kb % PF][0] = *reinterpret_cast<const float4*>(xp + (kb + PF) * 32);
                xb[kb % PF][1] = *reinterpret_cast<const float4*>(xp + (kb + PF) * 32 + 4);
            }
        }
        f32x4 acc = acc0 + acc1;

        // Combine K-halves: half 1 publishes, half 0 consumes.
        if (half == 1)
            *reinterpret_cast<f32x4*>(&s_acc[pair][lane][0]) = acc;
        __syncthreads();

        if (half == 0) {
            acc += *reinterpret_cast<const f32x4*>(&s_acc[pair][lane][0]);

            // Gather the other 4 experts from lane^16.
            const float p0 = __shfl_xor(acc[0], 16, 64);
            const float p1 = __shfl_xor(acc[1], 16, 64);
            const float p2 = __shfl_xor(acc[2], 16, 64);
            const float p3 = __shfl_xor(acc[3], 16, 64);

            if (lane < 16) {
                float lg[NE] = {acc[0], acc[1], acc[2], acc[3], p0, p1, p2, p3};
                const int bsel = (b == b0) ? 0 : 1;
#pragma unroll
                for (int e = 0; e < NE; ++e) lg[e] += s_pl[bsel][e];

                // softmax + entropy: ent = ln(S) - (sum p*l)/S, l = logit-max
                float m = lg[0];
#pragma unroll
                for (int e = 1; e < NE; ++e) m = fmaxf(m, lg[e]);
                float S = 0.f, dd = 0.f;
#pragma unroll
                for (int e = 0; e < NE; ++e) {
                    const float l = lg[e] - m;
                    const float p = __expf(l);
                    lg[e] = p;
                    S += p;
                    dd = fmaf(p, l, dd);
                }
                const float inv = 1.f / S;
                const float ent = __logf(S) - dd * inv;

                float4 q0 = {lg[0] * inv, lg[1] * inv, lg[2] * inv, lg[3] * inv};
                float4 q1 = {lg[4] * inv, lg[5] * inv, lg[6] * inv, lg[7] * inv};
                *reinterpret_cast<float4*>(probs_out + (size_t)token * NE)     = q0;
                *reinterpret_cast<float4*>(probs_out + (size_t)token * NE + 4) = q1;
                ent_out[token] = ent;
            }
        }
    } else {
        // ------------------------------ CLS head ----------------------------
        const int cb   = blockIdx.x - RBLKS;     // 0..255
        const int b    = cb >> 1;
        const int half = cb & 1;
        const int lane = t & 63;
        const int wv   = t >> 6;                 // 0..3

        __shared__ __align__(16) float s_x[ND];
        __shared__ float s_red[4];
        __shared__ float s_part[4][65];

        const float* xp = tokens + (size_t)b * NT_ALL * ND;  // cls token

        float sum = 0.f;
        for (int i = t; i < ND; i += 256) { float v = xp[i]; s_x[i] = v; sum += v; }
#pragma unroll
        for (int off = 32; off; off >>= 1) sum += __shfl_xor(sum, off, 64);
        if (lane == 0) s_red[wv] = sum;
        __syncthreads();
        const float mu = (s_red[0] + s_red[1] + s_red[2] + s_red[3]) * (1.f / ND);
        __syncthreads();

        float sq = 0.f;
        for (int i = t; i < ND; i += 256) { float d = s_x[i] - mu; sq += d * d; }
#pragma unroll
        for (int off = 32; off; off >>= 1) sq += __shfl_xor(sq, off, 64);
        if (lane == 0) s_red[wv] = sq;
        __syncthreads();
        const float var  = (s_red[0] + s_red[1] + s_red[2] + s_red[3]) * (1.f / ND);
        const float rstd = rsqrtf(var + 1e-5f);
        __syncthreads();

        for (int i = t; i < ND; i += 256)
            s_x[i] = (s_x[i] - mu) * rstd * ln_g[i] + ln_b[i];
        __syncthreads();

        const int c = half * 64 + lane;
        const float* wp; int st;
        if (c < NCLS)      { wp = cls_w + c;          st = NCLS; }
        else if (c < NCOL) { wp = aux_w + (c - NCLS); st = NORG; }
        else               { wp = aux_w;              st = NORG; }

        const int d0 = wv * 192;
        const float* w = wp + (size_t)d0 * st;
        const int st2 = 2 * st, st3 = 3 * st, st4 = 4 * st;
        float a0 = 0.f, a1 = 0.f, a2 = 0.f, a3 = 0.f;
#pragma unroll 8
        for (int j = 0; j < 192; j += 4) {
            const float4 x4 = *reinterpret_cast<const float4*>(&s_x[d0 + j]);
            a0 = fmaf(x4.x, w[0],   a0);
            a1 = fmaf(x4.y, w[st],  a1);
            a2 = fmaf(x4.z, w[st2], a2);
            a3 = fmaf(x4.w, w[st3], a3);
            w += st4;
        }
        s_part[wv][lane] = (a0 + a1) + (a2 + a3);
        __syncthreads();

        if (t < 64) {
            float r = s_part[0][t] + s_part[1][t] + s_part[2][t] + s_part[3][t];
            const int cc = half * 64 + t;
            if (cc < NCLS)
                out_logits[b * NCLS + cc] = r + cls_b[cc];
            else if (cc < NCOL)
                out_aux[b * NORG + (cc - NCLS)] = r + aux_b[cc - NCLS];
        }
    }
}

extern "C" void kernel_launch(void* const* d_in, const int* in_sizes, int n_in,
                              void* d_out, int out_size, void* d_ws, size_t ws_size,
                              hipStream_t stream) {
    const float* tokens = (const float*)d_in[0];
    const float* priors = (const float*)d_in[1];
    const float* rw     = (const float*)d_in[2];
    const float* rbias  = (const float*)d_in[3];
    // d_in[4..7] = w1,b1,w2,b2 : dead code (MoE output unused by reference)
    const float* ln_g   = (const float*)d_in[8];
    const float* ln_b   = (const float*)d_in[9];
    const float* cls_w  = (const float*)d_in[10];
    const float* cls_b  = (const float*)d_in[11];
    const float* aux_w  = (const float*)d_in[12];
    const float* aux_b  = (const float*)d_in[13];

    float* out = (float*)d_out;
    float* out_logits = out;                                   // 12800
    float* out_aux    = out + NB * NCLS;                       // +640
    float* out_probs  = out + NB * NCLS + NB * NORG;           // +200704
    float* out_ent    = out + NB * NCLS + NB * NORG + (size_t)NTOK * NE;

    fused_kernel<<<RBLKS + CBLKS, 256, 0, stream>>>(
        tokens, priors, rw, rbias, ln_g, ln_b, cls_w, cls_b, aux_w, aux_b,
        out_logits, out_aux, out_probs, out_ent);
}

// Round 9
// 27.662 us; speedup vs baseline: 1.0925x; 1.0700x over previous
//
#include <hip/hip_runtime.h>
#include <hip/hip_bf16.h>
#include <math.h>

// Problem constants (from reference)
#define NB     128
#define NT_ALL 197
#define NT     196
#define ND     768
#define NORG   5
#define NE     8
#define NCLS   100
#define NCOL   105            // 100 cls + 5 aux columns
#define NTOK   (NB * NT)      // 25088
#define KB     24             // 768 / 32 k-blocks total
#define KHALF  12             // k-blocks per wave (K split across wave pair)

#define RBLKS  784            // router blocks: 784 * 2 tiles * 16 tokens = 25088
#define CBLKS  256            // cls blocks after

typedef short  bf16x8 __attribute__((ext_vector_type(8)));
typedef float  f32x4  __attribute__((ext_vector_type(4)));

// Output layout (flat, concatenated in return order):
//   logits  : NB*NCLS = 12800   @ 0
//   aux_org : NB*NORG = 640     @ 12800
//   probs   : NTOK*NE = 200704  @ 13440
//   entropy : NTOK    = 25088   @ 214144

// ---------------------------------------------------------------------------
// Router-as-GEMM with K-split wave pairs and a REGISTER-RESIDENT load batch:
// all 24 x-loads (96 VGPRs) are issued back-to-back, pinned by
// sched_barrier(0) so the compiler cannot sink them; weight staging to LDS
// overlaps their latency; the K-loop then runs entirely from registers.
// ---------------------------------------------------------------------------
__global__ __launch_bounds__(256, 3) void fused_kernel(
    const float* __restrict__ tokens,    // (NB, NT_ALL, ND)
    const float* __restrict__ priors,    // (NB, NORG)
    const float* __restrict__ rw,        // (ND+NORG, NE) row-major
    const float* __restrict__ rbias,     // (NE,)
    const float* __restrict__ ln_g, const float* __restrict__ ln_b,
    const float* __restrict__ cls_w,     // (ND, NCLS)
    const float* __restrict__ cls_b,     // (NCLS,)
    const float* __restrict__ aux_w,     // (ND, NORG)
    const float* __restrict__ aux_b,     // (NORG,)
    float* __restrict__ out_logits,      // (NB, NCLS)
    float* __restrict__ out_aux,         // (NB, NORG)
    float* __restrict__ probs_out,       // (NTOK, NE)
    float* __restrict__ ent_out)         // (NTOK,)
{
    const int t = threadIdx.x;

    if (blockIdx.x < RBLKS) {
        // ------------------------------ router ------------------------------
        __shared__ __align__(16) __hip_bfloat16 s_a[KB * 4 * 16 * 8]; // 24KB
        __shared__ float s_pl[2][NE];
        __shared__ __align__(16) float s_acc[2][64][4];               // 2KB

        const int wid  = t >> 6;
        const int lane = t & 63;
        const int pair = wid >> 1;       // tile within block (0,1)
        const int half = wid & 1;        // K-half (0: kb 0-11, 1: kb 12-23)
        const int tt   = lane & 15;      // token col / expert row
        const int g    = lane >> 4;      // k-octet selector
        const int tok0 = blockIdx.x * 32;
        const int token = tok0 + pair * 16 + tt;
        const int b  = token / NT;
        const float* xp = tokens + ((size_t)b * NT_ALL + 1 + (token - b * NT)) * ND
                          + half * (KHALF * 32) + g * 8;

        // Issue ALL x-loads for this wave's K-half, back-to-back, into a
        // flat register array (static indices only -> stays in VGPRs).
        float4 x[2 * KHALF];             // 96 VGPRs of data in flight
#pragma unroll
        for (int i = 0; i < KHALF; ++i) {
            x[2 * i]     = *reinterpret_cast<const float4*>(xp + i * 32);
            x[2 * i + 1] = *reinterpret_cast<const float4*>(xp + i * 32 + 4);
        }
        // Hard scheduler fence: nothing below may move above; the loads
        // cannot be sunk toward their uses.
        __builtin_amdgcn_sched_barrier(0);

        // Zero-init ONLY the e>=8 padding rows (disjoint from fill below).
        {
            bf16x8 z = {0, 0, 0, 0, 0, 0, 0, 0};
            bf16x8* p = (bf16x8*)s_a;
            for (int i = t; i < KB * 4 * 8; i += 256)
                p[(i >> 3) * 16 + 8 + (i & 7)] = z;
        }
        // Fill real experts (e<8): coalesced rw reads, scattered b16 writes.
        for (int i = t; i < ND * NE; i += 256) {
            const int k = i >> 3, e = i & 7;
            const int kb = k >> 5, gg = (k >> 3) & 3, j = k & 7;
            s_a[(((kb * 4 + gg) * 16) + e) * 8 + j] = __float2bfloat16(rw[i]);
        }
        // Prior+bias logits for the (at most 2) batch rows this block spans.
        const int b0 = tok0 / NT;
        const int b1 = (tok0 + 31) / NT;
        if (t < 16) {
            const int e = t & 7, which = t >> 3;
            const int bb = which ? b1 : b0;
            float a = rbias[e];
#pragma unroll
            for (int o = 0; o < NORG; ++o)
                a = fmaf(priors[bb * NORG + o], rw[(ND + o) * NE + e], a);
            s_pl[which][e] = a;
        }
        __syncthreads();   // staging complete (x-loads may still be in flight)

        const bf16x8* s_a8 = (const bf16x8*)s_a + (half * KHALF * 4 + g) * 16 + tt;
        f32x4 acc0 = {0.f, 0.f, 0.f, 0.f};
        f32x4 acc1 = {0.f, 0.f, 0.f, 0.f};

#pragma unroll
        for (int kb = 0; kb < KHALF; ++kb) {
            const float4 x0 = x[2 * kb];
            const float4 x1 = x[2 * kb + 1];
            union { bf16x8 v; __hip_bfloat16 h[8]; } u;
            u.h[0] = __float2bfloat16(x0.x);
            u.h[1] = __float2bfloat16(x0.y);
            u.h[2] = __float2bfloat16(x0.z);
            u.h[3] = __float2bfloat16(x0.w);
            u.h[4] = __float2bfloat16(x1.x);
            u.h[5] = __float2bfloat16(x1.y);
            u.h[6] = __float2bfloat16(x1.z);
            u.h[7] = __float2bfloat16(x1.w);
            const bf16x8 af = s_a8[kb * 64];
            if (kb & 1)
                acc1 = __builtin_amdgcn_mfma_f32_16x16x32_bf16(af, u.v, acc1, 0, 0, 0);
            else
                acc0 = __builtin_amdgcn_mfma_f32_16x16x32_bf16(af, u.v, acc0, 0, 0, 0);
        }
        f32x4 acc = acc0 + acc1;

        // Combine K-halves: half 1 publishes, half 0 consumes.
        if (half == 1)
            *reinterpret_cast<f32x4*>(&s_acc[pair][lane][0]) = acc;
        __syncthreads();

        if (half == 0) {
            acc += *reinterpret_cast<const f32x4*>(&s_acc[pair][lane][0]);

            // Gather the other 4 experts from lane^16.
            const float p0 = __shfl_xor(acc[0], 16, 64);
            const float p1 = __shfl_xor(acc[1], 16, 64);
            const float p2 = __shfl_xor(acc[2], 16, 64);
            const float p3 = __shfl_xor(acc[3], 16, 64);

            if (lane < 16) {
                float lg[NE] = {acc[0], acc[1], acc[2], acc[3], p0, p1, p2, p3};
                const int bsel = (b == b0) ? 0 : 1;
#pragma unroll
                for (int e = 0; e < NE; ++e) lg[e] += s_pl[bsel][e];

                // softmax + entropy: ent = ln(S) - (sum p*l)/S, l = logit-max
                float m = lg[0];
#pragma unroll
                for (int e = 1; e < NE; ++e) m = fmaxf(m, lg[e]);
                float S = 0.f, dd = 0.f;
#pragma unroll
                for (int e = 0; e < NE; ++e) {
                    const float l = lg[e] - m;
                    const float p = __expf(l);
                    lg[e] = p;
                    S += p;
                    dd = fmaf(p, l, dd);
                }
                const float inv = 1.f / S;
                const float ent = __logf(S) - dd * inv;

                float4 q0 = {lg[0] * inv, lg[1] * inv, lg[2] * inv, lg[3] * inv};
                float4 q1 = {lg[4] * inv, lg[5] * inv, lg[6] * inv, lg[7] * inv};
                *reinterpret_cast<float4*>(probs_out + (size_t)token * NE)     = q0;
                *reinterpret_cast<float4*>(probs_out + (size_t)token * NE + 4) = q1;
                ent_out[token] = ent;
            }
        }
    } else {
        // ------------------------------ CLS head ----------------------------
        const int cb   = blockIdx.x - RBLKS;     // 0..255
        const int b    = cb >> 1;
        const int half = cb & 1;
        const int lane = t & 63;
        const int wv   = t >> 6;                 // 0..3

        __shared__ __align__(16) float s_x[ND];
        __shared__ float s_red[4];
        __shared__ float s_part[4][65];

        const float* xp = tokens + (size_t)b * NT_ALL * ND;  // cls token

        float sum = 0.f;
        for (int i = t; i < ND; i += 256) { float v = xp[i]; s_x[i] = v; sum += v; }
#pragma unroll
        for (int off = 32; off; off >>= 1) sum += __shfl_xor(sum, off, 64);
        if (lane == 0) s_red[wv] = sum;
        __syncthreads();
        const float mu = (s_red[0] + s_red[1] + s_red[2] + s_red[3]) * (1.f / ND);
        __syncthreads();

        float sq = 0.f;
        for (int i = t; i < ND; i += 256) { float d = s_x[i] - mu; sq += d * d; }
#pragma unroll
        for (int off = 32; off; off >>= 1) sq += __shfl_xor(sq, off, 64);
        if (lane == 0) s_red[wv] = sq;
        __syncthreads();
        const float var  = (s_red[0] + s_red[1] + s_red[2] + s_red[3]) * (1.f / ND);
        const float rstd = rsqrtf(var + 1e-5f);
        __syncthreads();

        for (int i = t; i < ND; i += 256)
            s_x[i] = (s_x[i] - mu) * rstd * ln_g[i] + ln_b[i];
        __syncthreads();

        const int c = half * 64 + lane;
        const float* wp; int st;
        if (c < NCLS)      { wp = cls_w + c;          st = NCLS; }
        else if (c < NCOL) { wp = aux_w + (c - NCLS); st = NORG; }
        else               { wp = aux_w;              st = NORG; }

        const int d0 = wv * 192;
        const float* w = wp + (size_t)d0 * st;
        const int st2 = 2 * st, st3 = 3 * st, st4 = 4 * st;
        float a0 = 0.f, a1 = 0.f, a2 = 0.f, a3 = 0.f;
#pragma unroll 8
        for (int j = 0; j < 192; j += 4) {
            const float4 x4 = *reinterpret_cast<const float4*>(&s_x[d0 + j]);
            a0 = fmaf(x4.x, w[0],   a0);
            a1 = fmaf(x4.y, w[st],  a1);
            a2 = fmaf(x4.z, w[st2], a2);
            a3 = fmaf(x4.w, w[st3], a3);
            w += st4;
        }
        s_part[wv][lane] = (a0 + a1) + (a2 + a3);
        __syncthreads();

        if (t < 64) {
            float r = s_part[0][t] + s_part[1][t] + s_part[2][t] + s_part[3][t];
            const int cc = half * 64 + t;
            if (cc < NCLS)
                out_logits[b * NCLS + cc] = r + cls_b[cc];
            else if (cc < NCOL)
                out_aux[b * NORG + (cc - NCLS)] = r + aux_b[cc - NCLS];
        }
    }
}

extern "C" void kernel_launch(void* const* d_in, const int* in_sizes, int n_in,
                              void* d_out, int out_size, void* d_ws, size_t ws_size,
                              hipStream_t stream) {
    const float* tokens = (const float*)d_in[0];
    const float* priors = (const float*)d_in[1];
    const float* rw     = (const float*)d_in[2];
    const float* rbias  = (const float*)d_in[3];
    // d_in[4..7] = w1,b1,w2,b2 : dead code (MoE output unused by reference)
    const float* ln_g   = (const float*)d_in[8];
    const float* ln_b   = (const float*)d_in[9];
    const float* cls_w  = (const float*)d_in[10];
    const float* cls_b  = (const float*)d_in[11];
    const float* aux_w  = (const float*)d_in[12];
    const float* aux_b  = (const float*)d_in[13];

    float* out = (float*)d_out;
    float* out_logits = out;                                   // 12800
    float* out_aux    = out + NB * NCLS;                       // +640
    float* out_probs  = out + NB * NCLS + NB * NORG;           // +200704
    float* out_ent    = out + NB * NCLS + NB * NORG + (size_t)NTOK * NE;

    fused_kernel<<<RBLKS + CBLKS, 256, 0, stream>>>(
        tokens, priors, rw, rbias, ln_g, ln_b, cls_w, cls_b, aux_w, aux_b,
        out_logits, out_aux, out_probs, out_ent);
}

// Round 10
// 26.870 us; speedup vs baseline: 1.1247x; 1.0295x over previous
//
#include <hip/hip_runtime.h>
#include <hip/hip_bf16.h>
#include <math.h>

// Problem constants (from reference)
#define NB     128
#define NT_ALL 197
#define NT     196
#define ND     768
#define NORG   5
#define NE     8
#define NCLS   100
#define NCOL   105            // 100 cls + 5 aux columns
#define NTOK   (NB * NT)      // 25088
#define KB     24             // 768 / 32 k-blocks total
#define KHALF  12             // k-blocks per wave (K split across wave pair)
#define XROW   776            // LDS row stride in bf16 elems (768 + 8 pad)

#define RBLKS  784            // router blocks: 784 * 32 tokens = 25088
#define CBLKS  256            // cls blocks after

typedef short  bf16x8 __attribute__((ext_vector_type(8)));
typedef float  f32x4  __attribute__((ext_vector_type(4)));

// Output layout (flat, concatenated in return order):
//   logits  : NB*NCLS = 12800   @ 0
//   aux_org : NB*NORG = 640     @ 12800
//   probs   : NTOK*NE = 200704  @ 13440
//   entropy : NTOK    = 25088   @ 214144

struct SharedRouter {
    __hip_bfloat16 x[32 * XROW];          // 48.5 KB token tile, bf16 row-major
    __hip_bfloat16 a[KB * 4 * 16 * 8];    // 24 KB weight A-fragments
    float pl[2][NE];
    float acc[2][64][4];
};
struct SharedCls {
    float x[ND];
    float red[4];
    float part[4][65];
};

// ---------------------------------------------------------------------------
// Router: 32 consecutive tokens per block = 96 KB of CONTIGUOUS global memory
// (row = gt + b + 1 absorbs the per-batch CLS row). Staged with pure
// wave-linear float4 streaming (the 6.3 TB/s pattern), converted to bf16 into
// LDS; MFMA K-loop (K split across wave pairs) then runs entirely from LDS.
// ---------------------------------------------------------------------------
__global__ __launch_bounds__(256, 4) void fused_kernel(
    const float* __restrict__ tokens,    // (NB, NT_ALL, ND)
    const float* __restrict__ priors,    // (NB, NORG)
    const float* __restrict__ rw,        // (ND+NORG, NE) row-major
    const float* __restrict__ rbias,     // (NE,)
    const float* __restrict__ ln_g, const float* __restrict__ ln_b,
    const float* __restrict__ cls_w,     // (ND, NCLS)
    const float* __restrict__ cls_b,     // (NCLS,)
    const float* __restrict__ aux_w,     // (ND, NORG)
    const float* __restrict__ aux_b,     // (NORG,)
    float* __restrict__ out_logits,      // (NB, NCLS)
    float* __restrict__ out_aux,         // (NB, NORG)
    float* __restrict__ probs_out,       // (NTOK, NE)
    float* __restrict__ ent_out)         // (NTOK,)
{
    __shared__ union { SharedRouter r; SharedCls c; } sm;
    const int t = threadIdx.x;

    if (blockIdx.x < RBLKS) {
        // ------------------------------ router ------------------------------
        const int tok0 = blockIdx.x * 32;

        // ---- Stage X: 6144 float4, wave-linear streaming reads ----
#pragma unroll 6
        for (int i = t; i < 32 * ND / 4; i += 256) {
            const int tok = i / 192;             // 192 float4 per token row
            const int k   = (i - tok * 192) * 4; // f32 col
            const int gt  = tok0 + tok;
            const int b   = gt / NT;
            const float4 v = *reinterpret_cast<const float4*>(
                tokens + (size_t)(gt + b + 1) * ND + k);
            union { __hip_bfloat16 h[4]; ushort4 u; } pk;
            pk.h[0] = __float2bfloat16(v.x);
            pk.h[1] = __float2bfloat16(v.y);
            pk.h[2] = __float2bfloat16(v.z);
            pk.h[3] = __float2bfloat16(v.w);
            *reinterpret_cast<ushort4*>(&sm.r.x[tok * XROW + k]) = pk.u;
        }

        // ---- Stage W: zero-pad rows e>=8, fill e<8 ----
        {
            bf16x8 z = {0, 0, 0, 0, 0, 0, 0, 0};
            bf16x8* p = (bf16x8*)sm.r.a;
            for (int i = t; i < KB * 4 * 8; i += 256)
                p[(i >> 3) * 16 + 8 + (i & 7)] = z;
        }
        for (int i = t; i < ND * NE; i += 256) {
            const int k = i >> 3, e = i & 7;
            const int kb = k >> 5, gg = (k >> 3) & 3, j = k & 7;
            sm.r.a[(((kb * 4 + gg) * 16) + e) * 8 + j] = __float2bfloat16(rw[i]);
        }
        // Prior+bias logits for the (at most 2) batch rows this block spans.
        const int b0 = tok0 / NT;
        const int b1 = (tok0 + 31) / NT;
        if (t < 16) {
            const int e = t & 7, which = t >> 3;
            const int bb = which ? b1 : b0;
            float a = rbias[e];
#pragma unroll
            for (int o = 0; o < NORG; ++o)
                a = fmaf(priors[bb * NORG + o], rw[(ND + o) * NE + e], a);
            sm.r.pl[which][e] = a;
        }
        __syncthreads();   // staging complete

        // ---- Compute: wave (pair, half); 16-token tile, 12 kb K-half ----
        const int wid  = t >> 6;
        const int lane = t & 63;
        const int pair = wid >> 1;
        const int half = wid & 1;
        const int tt   = lane & 15;
        const int g    = lane >> 4;
        const int token = tok0 + pair * 16 + tt;
        const int b  = token / NT;

        const bf16x8* s_a8 =
            (const bf16x8*)sm.r.a + (half * KHALF * 4 + g) * 16 + tt;
        const __hip_bfloat16* xrow =
            sm.r.x + (pair * 16 + tt) * XROW + half * (KHALF * 32) + g * 8;

        f32x4 acc0 = {0.f, 0.f, 0.f, 0.f};
        f32x4 acc1 = {0.f, 0.f, 0.f, 0.f};
#pragma unroll
        for (int kb = 0; kb < KHALF; ++kb) {
            const bf16x8 xf = *reinterpret_cast<const bf16x8*>(xrow + kb * 32);
            const bf16x8 af = s_a8[kb * 64];
            if (kb & 1)
                acc1 = __builtin_amdgcn_mfma_f32_16x16x32_bf16(af, xf, acc1, 0, 0, 0);
            else
                acc0 = __builtin_amdgcn_mfma_f32_16x16x32_bf16(af, xf, acc0, 0, 0, 0);
        }
        f32x4 acc = acc0 + acc1;

        // Combine K-halves: half 1 publishes, half 0 consumes.
        if (half == 1)
            *reinterpret_cast<f32x4*>(&sm.r.acc[pair][lane][0]) = acc;
        __syncthreads();

        if (half == 0) {
            acc += *reinterpret_cast<const f32x4*>(&sm.r.acc[pair][lane][0]);

            // Gather the other 4 experts from lane^16.
            const float p0 = __shfl_xor(acc[0], 16, 64);
            const float p1 = __shfl_xor(acc[1], 16, 64);
            const float p2 = __shfl_xor(acc[2], 16, 64);
            const float p3 = __shfl_xor(acc[3], 16, 64);

            if (lane < 16) {
                float lg[NE] = {acc[0], acc[1], acc[2], acc[3], p0, p1, p2, p3};
                const int bsel = (b == b0) ? 0 : 1;
#pragma unroll
                for (int e = 0; e < NE; ++e) lg[e] += sm.r.pl[bsel][e];

                // softmax + entropy: ent = ln(S) - (sum p*l)/S, l = logit-max
                float m = lg[0];
#pragma unroll
                for (int e = 1; e < NE; ++e) m = fmaxf(m, lg[e]);
                float S = 0.f, dd = 0.f;
#pragma unroll
                for (int e = 0; e < NE; ++e) {
                    const float l = lg[e] - m;
                    const float p = __expf(l);
                    lg[e] = p;
                    S += p;
                    dd = fmaf(p, l, dd);
                }
                const float inv = 1.f / S;
                const float ent = __logf(S) - dd * inv;

                float4 q0 = {lg[0] * inv, lg[1] * inv, lg[2] * inv, lg[3] * inv};
                float4 q1 = {lg[4] * inv, lg[5] * inv, lg[6] * inv, lg[7] * inv};
                *reinterpret_cast<float4*>(probs_out + (size_t)token * NE)     = q0;
                *reinterpret_cast<float4*>(probs_out + (size_t)token * NE + 4) = q1;
                ent_out[token] = ent;
            }
        }
    } else {
        // ------------------------------ CLS head ----------------------------
        const int cb   = blockIdx.x - RBLKS;     // 0..255
        const int b    = cb >> 1;
        const int half = cb & 1;
        const int lane = t & 63;
        const int wv   = t >> 6;                 // 0..3

        const float* xp = tokens + (size_t)b * NT_ALL * ND;  // cls token

        float sum = 0.f;
        for (int i = t; i < ND; i += 256) { float v = xp[i]; sm.c.x[i] = v; sum += v; }
#pragma unroll
        for (int off = 32; off; off >>= 1) sum += __shfl_xor(sum, off, 64);
        if (lane == 0) sm.c.red[wv] = sum;
        __syncthreads();
        const float mu = (sm.c.red[0] + sm.c.red[1] + sm.c.red[2] + sm.c.red[3]) * (1.f / ND);
        __syncthreads();

        float sq = 0.f;
        for (int i = t; i < ND; i += 256) { float d = sm.c.x[i] - mu; sq += d * d; }
#pragma unroll
        for (int off = 32; off; off >>= 1) sq += __shfl_xor(sq, off, 64);
        if (lane == 0) sm.c.red[wv] = sq;
        __syncthreads();
        const float var  = (sm.c.red[0] + sm.c.red[1] + sm.c.red[2] + sm.c.red[3]) * (1.f / ND);
        const float rstd = rsqrtf(var + 1e-5f);
        __syncthreads();

        for (int i = t; i < ND; i += 256)
            sm.c.x[i] = (sm.c.x[i] - mu) * rstd * ln_g[i] + ln_b[i];
        __syncthreads();

        const int c = half * 64 + lane;
        const float* wp; int st;
        if (c < NCLS)      { wp = cls_w + c;          st = NCLS; }
        else if (c < NCOL) { wp = aux_w + (c - NCLS); st = NORG; }
        else               { wp = aux_w;              st = NORG; }

        const int d0 = wv * 192;
        const float* w = wp + (size_t)d0 * st;
        const int st2 = 2 * st, st3 = 3 * st, st4 = 4 * st;
        float a0 = 0.f, a1 = 0.f, a2 = 0.f, a3 = 0.f;
#pragma unroll 8
        for (int j = 0; j < 192; j += 4) {
            const float4 x4 = *reinterpret_cast<const float4*>(&sm.c.x[d0 + j]);
            a0 = fmaf(x4.x, w[0],   a0);
            a1 = fmaf(x4.y, w[st],  a1);
            a2 = fmaf(x4.z, w[st2], a2);
            a3 = fmaf(x4.w, w[st3], a3);
            w += st4;
        }
        sm.c.part[wv][lane] = (a0 + a1) + (a2 + a3);
        __syncthreads();

        if (t < 64) {
            float r = sm.c.part[0][t] + sm.c.part[1][t] + sm.c.part[2][t] + sm.c.part[3][t];
            const int cc = half * 64 + t;
            if (cc < NCLS)
                out_logits[b * NCLS + cc] = r + cls_b[cc];
            else if (cc < NCOL)
                out_aux[b * NORG + (cc - NCLS)] = r + aux_b[cc - NCLS];
        }
    }
}

extern "C" void kernel_launch(void* const* d_in, const int* in_sizes, int n_in,
                              void* d_out, int out_size, void* d_ws, size_t ws_size,
                              hipStream_t stream) {
    const float* tokens = (const float*)d_in[0];
    const float* priors = (const float*)d_in[1];
    const float* rw     = (const float*)d_in[2];
    const float* rbias  = (const float*)d_in[3];
    // d_in[4..7] = w1,b1,w2,b2 : dead code (MoE output unused by reference)
    const float* ln_g   = (const float*)d_in[8];
    const float* ln_b   = (const float*)d_in[9];
    const float* cls_w  = (const float*)d_in[10];
    const float* cls_b  = (const float*)d_in[11];
    const float* aux_w  = (const float*)d_in[12];
    const float* aux_b  = (const float*)d_in[13];

    float* out = (float*)d_out;
    float* out_logits = out;                                   // 12800
    float* out_aux    = out + NB * NCLS;                       // +640
    float* out_probs  = out + NB * NCLS + NB * NORG;           // +200704
    float* out_ent    = out + NB * NCLS + NB * NORG + (size_t)NTOK * NE;

    fused_kernel<<<RBLKS + CBLKS, 256, 0, stream>>>(
        tokens, priors, rw, rbias, ln_g, ln_b, cls_w, cls_b, aux_w, aux_b,
        out_logits, out_aux, out_probs, out_ent);
}